// Round 1
// baseline (1365.661 us; speedup 1.0000x reference)
//
#include <hip/hip_runtime.h>
#include <hip/hip_bf16.h>

// Problem: B=8, S=128, D=1024, H=4096, TOPK=256 -> k = 32768 per batch over S*H=524288 scores.
#define B_  8
#define S_  128
#define D_  1024
#define H_  4096
#define M_  (B_ * S_)          // 1024 flattened rows
#define NSCORE   (M_ * H_)     // 4,194,304 score entries
#define PERBATCH (S_ * H_)     // 524,288 per batch
#define TOPK_K   (256 * S_)    // 32,768

// ---------------- workspace layout (bytes, all 256-aligned) ----------------
#define G_OFF    0u                       // g (fp32 1024x4096, 16MB); later reused as h_prev
#define SC_OFF   16777216u                // scores (fp32 16MB); later reused as h_curr
#define XB_OFF   33554432u                // x bf16 (2MB)
#define WP_OFF   35651584u                // up_prev bf16 (8MB)
#define WC_OFF   44040192u                // up_curr bf16 (8MB)
#define WD_OFF   52428800u                // down_w bf16 (8MB)
#define ACT_OFF  60817408u                // act bf16 (8MB)
#define H1_OFF   69206016u                // hist level1: 8 x 65536 u32 (2MB)
#define H2_OFF   71303168u                // hist level2: 8 x 65536 u32 (2MB)
#define SEL_OFF  73400320u                // sel: 8 x 4096 u32 (128KB)
#define SCAL_OFF 73531392u                // B1[8],K1[8],B2[8],K2[8],TIEN[8]
#define TIE_OFF  (SCAL_OFF + 256u)       // tieIdx: 8 x 2048 u32 (64KB)
// total ~73.6 MB

typedef __attribute__((ext_vector_type(8))) short short8;   // 8 bf16 (4 VGPRs)
typedef __attribute__((ext_vector_type(4))) float f32x4;

// monotone mapping fp32 -> u32 (larger key == larger float)
__device__ __forceinline__ unsigned tokey(float f) {
    unsigned u = __float_as_uint(f);
    return (u & 0x80000000u) ? ~u : (u | 0x80000000u);
}

// ---------------- fp32 -> bf16 convert (vectorized x4) ----------------
__global__ __launch_bounds__(256) void f2bf_kernel(const float* __restrict__ in,
                                                   __hip_bfloat16* __restrict__ out, int n4) {
    int i = blockIdx.x * 256 + threadIdx.x;
    if (i >= n4) return;
    float4 v = *(const float4*)(in + (size_t)i * 4);
    out[(size_t)i*4+0] = __float2bfloat16(v.x);
    out[(size_t)i*4+1] = __float2bfloat16(v.y);
    out[(size_t)i*4+2] = __float2bfloat16(v.z);
    out[(size_t)i*4+3] = __float2bfloat16(v.w);
}

// ---------------- fp32 tiled GEMM: C[m,n] = A[m,:] . B[n,:] + bias[n] ----------------
// A [M,K] row-major, B [N,K] row-major (i.e. B^T operand). 128x128 tile, BK=16, 256 thr, 8x8/thread.
template <int RELU>
__global__ __launch_bounds__(256) void sgemm_bt_kernel(const float* __restrict__ A,
                                                       const float* __restrict__ Bm,
                                                       const float* __restrict__ bias,
                                                       float* __restrict__ C, int N, int K) {
    __shared__ float As[16][132];
    __shared__ float Bs[16][132];
    const int tid  = threadIdx.x;
    const int row0 = blockIdx.y * 128, col0 = blockIdx.x * 128;
    const int ty = tid >> 4, tx = tid & 15;
    const int r_ld = tid >> 2;          // 0..63
    const int c_ld = (tid & 3) * 4;     // 0,4,8,12
    float acc[8][8] = {};
    for (int kt = 0; kt < K; kt += 16) {
        #pragma unroll
        for (int half = 0; half < 2; half++) {
            int r = half * 64 + r_ld;
            float4 va = *(const float4*)(A  + (size_t)(row0 + r) * K + kt + c_ld);
            float4 vb = *(const float4*)(Bm + (size_t)(col0 + r) * K + kt + c_ld);
            As[c_ld+0][r] = va.x; As[c_ld+1][r] = va.y; As[c_ld+2][r] = va.z; As[c_ld+3][r] = va.w;
            Bs[c_ld+0][r] = vb.x; Bs[c_ld+1][r] = vb.y; Bs[c_ld+2][r] = vb.z; Bs[c_ld+3][r] = vb.w;
        }
        __syncthreads();
        #pragma unroll
        for (int k = 0; k < 16; k++) {
            float a[8], b[8];
            *(float4*)(a)   = *(const float4*)&As[k][ty*8];
            *(float4*)(a+4) = *(const float4*)&As[k][ty*8+4];
            *(float4*)(b)   = *(const float4*)&Bs[k][tx*8];
            *(float4*)(b+4) = *(const float4*)&Bs[k][tx*8+4];
            #pragma unroll
            for (int i = 0; i < 8; i++)
                #pragma unroll
                for (int j = 0; j < 8; j++)
                    acc[i][j] += a[i] * b[j];
        }
        __syncthreads();
    }
    #pragma unroll
    for (int i = 0; i < 8; i++) {
        int row = row0 + ty*8 + i;
        #pragma unroll
        for (int j = 0; j < 8; j++) {
            int col = col0 + tx*8 + j;
            float v = acc[i][j] + (bias ? bias[col] : 0.0f);
            if (RELU) v = v > 0.0f ? v : 0.0f;
            C[(size_t)row * N + col] = v;
        }
    }
}

// ---------------- bf16 MFMA GEMM (m97-style): C = A . B^T (+bias) ----------------
// A [M,K] bf16 row-major, B [N,K] bf16 row-major. 128x128 tile, BK=32, 4 waves (2x2 of 64x64).
// blockIdx.z selects (B,C) pair so up_prev/up_curr run as one launch.
__global__ __launch_bounds__(256) void bgemm_bt_kernel(const short* __restrict__ A,
                                                       const short* __restrict__ B0,
                                                       const short* __restrict__ B1,
                                                       float* __restrict__ C0,
                                                       float* __restrict__ C1,
                                                       const float* __restrict__ bias,
                                                       int N, int K) {
    const short* Bw = (blockIdx.z == 0) ? B0 : B1;
    float*       C  = (blockIdx.z == 0) ? C0 : C1;
    __shared__ short As[128 * 32];
    __shared__ short Bs[128 * 32];
    const int tid  = threadIdx.x;
    const int lane = tid & 63;
    const int wave = tid >> 6;
    const int wr = wave >> 1, wc = wave & 1;
    const int row0 = blockIdx.y * 128, col0 = blockIdx.x * 128;
    const int r_ld = tid >> 2;         // 0..63
    const int c_ld = (tid & 3) * 8;    // short offset: 0,8,16,24
    f32x4 acc[4][4] = {};
    for (int kt = 0; kt < K; kt += 32) {
        #pragma unroll
        for (int half = 0; half < 2; half++) {
            int r = half * 64 + r_ld;
            __builtin_amdgcn_global_load_lds(
                (const __attribute__((address_space(1))) unsigned*)(A + (size_t)(row0 + r) * K + kt + c_ld),
                (__attribute__((address_space(3))) unsigned*)(As + r * 32 + c_ld), 16, 0, 0);
            __builtin_amdgcn_global_load_lds(
                (const __attribute__((address_space(1))) unsigned*)(Bw + (size_t)(col0 + r) * K + kt + c_ld),
                (__attribute__((address_space(3))) unsigned*)(Bs + r * 32 + c_ld), 16, 0, 0);
        }
        __syncthreads();
        short8 af[4], bfr[4];
        #pragma unroll
        for (int t = 0; t < 4; t++) {
            af[t]  = *(const short8*)(As + (wr*64 + t*16 + (lane & 15)) * 32 + (lane >> 4) * 8);
            bfr[t] = *(const short8*)(Bs + (wc*64 + t*16 + (lane & 15)) * 32 + (lane >> 4) * 8);
        }
        #pragma unroll
        for (int tm = 0; tm < 4; tm++)
            #pragma unroll
            for (int tn = 0; tn < 4; tn++)
                acc[tm][tn] = __builtin_amdgcn_mfma_f32_16x16x32_bf16(af[tm], bfr[tn], acc[tm][tn], 0, 0, 0);
        __syncthreads();
    }
    // C/D layout: col = lane&15, row = (lane>>4)*4 + reg  [measured m89/m91]
    #pragma unroll
    for (int tm = 0; tm < 4; tm++) {
        int row = row0 + wr*64 + tm*16 + (lane >> 4) * 4;
        #pragma unroll
        for (int tn = 0; tn < 4; tn++) {
            int col = col0 + wc*64 + tn*16 + (lane & 15);
            float bv = bias ? bias[col] : 0.0f;
            #pragma unroll
            for (int r = 0; r < 4; r++)
                C[(size_t)(row + r) * N + col] = acc[tm][tn][r] + bv;
        }
    }
}

// ---------------- top-k radix-select ----------------
__global__ __launch_bounds__(256) void hist1_kernel(const float* __restrict__ scores,
                                                    unsigned* __restrict__ hist) {
    int i = blockIdx.x * 256 + threadIdx.x;
    if (i >= NSCORE) return;
    int b = i >> 19;
    unsigned key = tokey(scores[i]);
    atomicAdd(&hist[(b << 16) + (key >> 16)], 1u);
}

__global__ __launch_bounds__(256) void hist2_kernel(const float* __restrict__ scores,
                                                    const unsigned* __restrict__ P1,
                                                    unsigned* __restrict__ hist2) {
    int i = blockIdx.x * 256 + threadIdx.x;
    if (i >= NSCORE) return;
    int b = i >> 19;
    unsigned key = tokey(scores[i]);
    if ((key >> 16) == P1[b]) atomicAdd(&hist2[(b << 16) + (key & 0xFFFFu)], 1u);
}

// one block per batch; finds bin where cumulative-from-top reaches k, and remainder k'
__global__ __launch_bounds__(256) void scan_hist_kernel(const unsigned* __restrict__ hist,
                                                        const unsigned* __restrict__ kin,
                                                        unsigned* __restrict__ binOut,
                                                        unsigned* __restrict__ kOut,
                                                        unsigned kconst) {
    int b = blockIdx.x, tid = threadIdx.x;
    const unsigned* h = hist + ((size_t)b << 16);
    unsigned k = kin ? kin[b] : kconst;
    __shared__ unsigned S[256];
    __shared__ int tstar;
    unsigned s = 0;
    const unsigned* seg = h + tid * 256;
    for (int i = 0; i < 256; i++) s += seg[i];
    S[tid] = s;
    __syncthreads();
    // inclusive suffix scan (Hillis-Steele)
    for (int off = 1; off < 256; off <<= 1) {
        unsigned a = S[tid];
        unsigned v = (tid + off < 256) ? S[tid + off] : 0u;
        __syncthreads();
        S[tid] = a + v;
        __syncthreads();
    }
    unsigned St = S[tid];
    unsigned Sn = (tid < 255) ? S[tid + 1] : 0u;
    if (St >= k && (tid == 255 || Sn < k)) tstar = tid;   // exactly one thread (S monotone)
    __syncthreads();
    if (tid == 0) {
        int t = tstar;
        unsigned runn = (t < 255) ? S[t + 1] : 0u;
        unsigned bin = (unsigned)t * 256u, kprime = 1u;
        for (int i = 255; i >= 0; i--) {
            unsigned c = h[t * 256 + i];
            if (runn + c >= k) { bin = (unsigned)(t * 256 + i); kprime = k - runn; break; }
            runn += c;
        }
        binOut[b] = bin;
        kOut[b]  = kprime;
    }
}

__global__ __launch_bounds__(256) void mark_kernel(const float* __restrict__ scores,
                                                   const unsigned* __restrict__ B1,
                                                   const unsigned* __restrict__ B2,
                                                   unsigned* __restrict__ sel,
                                                   unsigned* __restrict__ tieN,
                                                   unsigned* __restrict__ tieIdx) {
    int i = blockIdx.x * 256 + threadIdx.x;
    if (i >= NSCORE) return;
    int b = i >> 19;
    unsigned TK = (B1[b] << 16) | B2[b];
    unsigned key = tokey(scores[i]);
    int hcol = i & (H_ - 1);
    if (key > TK) {
        sel[(b << 12) + hcol] = 1u;              // benign write race (same value)
    } else if (key == TK) {
        unsigned slot = atomicAdd(&tieN[b], 1u);
        if (slot < 2048u) tieIdx[(b << 11) + slot] = (unsigned)(i & (PERBATCH - 1));
    }
}

// ties: take the K2[b] smallest flat indices among key==threshold (jax top_k tie-break)
__global__ void ties_kernel(const unsigned* __restrict__ K2,
                            const unsigned* __restrict__ tieN,
                            const unsigned* __restrict__ tieIdx,
                            unsigned* __restrict__ sel) {
    int b = threadIdx.x;
    if (b >= B_) return;
    unsigned n = tieN[b]; if (n > 2048u) n = 2048u;
    unsigned need = K2[b]; if (need > n) need = n;
    if (need == n) {                // common case: no real collision beyond what we take
        for (unsigned j = 0; j < n; j++)
            sel[(b << 12) + (tieIdx[(b << 11) + j] & (H_ - 1))] = 1u;
        return;
    }
    unsigned last = 0;
    for (unsigned c = 0; c < need; c++) {
        unsigned best = 0xFFFFFFFFu;
        for (unsigned j = 0; j < n; j++) {
            unsigned v = tieIdx[(b << 11) + j];
            if (v >= last && v < best) best = v;
        }
        sel[(b << 12) + (best & (H_ - 1))] = 1u;
        last = best + 1u;
    }
}

// ---------------- select + bias + exact GELU -> bf16 ----------------
__global__ __launch_bounds__(256) void act_kernel(const float* __restrict__ hprev,
                                                  const float* __restrict__ hcurr,
                                                  const float* __restrict__ bprev,
                                                  const float* __restrict__ bcurr,
                                                  const unsigned* __restrict__ sel,
                                                  __hip_bfloat16* __restrict__ act) {
    int i = blockIdx.x * 256 + threadIdx.x;
    if (i >= NSCORE) return;
    int h = i & (H_ - 1);
    int b = i >> 19;
    float v = sel[(b << 12) + h] ? (hprev[i] + bprev[h]) : (hcurr[i] + bcurr[h]);
    float gl = 0.5f * v * (1.0f + erff(v * 0.70710678118654752440f));
    act[i] = __float2bfloat16(gl);
}

extern "C" void kernel_launch(void* const* d_in, const int* in_sizes, int n_in,
                              void* d_out, int out_size, void* d_ws, size_t ws_size,
                              hipStream_t stream) {
    const float* x     = (const float*)d_in[0];
    const float* wprev = (const float*)d_in[1];
    const float* bprev = (const float*)d_in[2];
    const float* wcurr = (const float*)d_in[3];
    const float* bcurr = (const float*)d_in[4];
    const float* gw1   = (const float*)d_in[5];
    const float* gb1   = (const float*)d_in[6];
    const float* gw2   = (const float*)d_in[7];
    const float* gb2   = (const float*)d_in[8];
    const float* dw    = (const float*)d_in[9];
    const float* db    = (const float*)d_in[10];
    float* out = (float*)d_out;
    char* ws = (char*)d_ws;

    float* g      = (float*)(ws + G_OFF);
    float* scores = (float*)(ws + SC_OFF);
    float* hprev  = (float*)(ws + G_OFF);    // g dead after gate GEMM2
    float* hcurr  = (float*)(ws + SC_OFF);   // scores dead after top-k marking
    __hip_bfloat16* xb  = (__hip_bfloat16*)(ws + XB_OFF);
    __hip_bfloat16* wpb = (__hip_bfloat16*)(ws + WP_OFF);
    __hip_bfloat16* wcb = (__hip_bfloat16*)(ws + WC_OFF);
    __hip_bfloat16* wdb = (__hip_bfloat16*)(ws + WD_OFF);
    __hip_bfloat16* act = (__hip_bfloat16*)(ws + ACT_OFF);
    unsigned* hist1  = (unsigned*)(ws + H1_OFF);
    unsigned* hist2  = (unsigned*)(ws + H2_OFF);
    unsigned* sel    = (unsigned*)(ws + SEL_OFF);
    unsigned* B1c    = (unsigned*)(ws + SCAL_OFF);
    unsigned* K1c    = (unsigned*)(ws + SCAL_OFF + 32);
    unsigned* B2c    = (unsigned*)(ws + SCAL_OFF + 64);
    unsigned* K2c    = (unsigned*)(ws + SCAL_OFF + 96);
    unsigned* TIEN   = (unsigned*)(ws + SCAL_OFF + 128);
    unsigned* tieIdx = (unsigned*)(ws + TIE_OFF);

    // bf16 copies of x and value-path weights
    f2bf_kernel<<<(M_*D_/4 + 255)/256, 256, 0, stream>>>(x,     xb,  M_*D_/4);
    f2bf_kernel<<<(H_*D_/4 + 255)/256, 256, 0, stream>>>(wprev, wpb, H_*D_/4);
    f2bf_kernel<<<(H_*D_/4 + 255)/256, 256, 0, stream>>>(wcurr, wcb, H_*D_/4);
    f2bf_kernel<<<(H_*D_/4 + 255)/256, 256, 0, stream>>>(dw,    wdb, H_*D_/4);

    // gate path in fp32 (top-k boundary needs ~1e-6 score accuracy)
    sgemm_bt_kernel<1><<<dim3(H_/128, M_/128), 256, 0, stream>>>(x, gw1, gb1, g,      H_, D_);
    sgemm_bt_kernel<0><<<dim3(H_/128, M_/128), 256, 0, stream>>>(g, gw2, gb2, scores, H_, H_);

    // top-k radix select -> sel[b][h]
    hipMemsetAsync(ws + H1_OFF, 0, (size_t)(H2_OFF - H1_OFF) + (1u<<21), stream); // hist1+hist2 (4MB)
    hipMemsetAsync(ws + SEL_OFF, 0, (size_t)(TIE_OFF - SEL_OFF) + 8u*2048u*4u, stream); // sel+scalars+ties
    hist1_kernel<<<NSCORE/256, 256, 0, stream>>>(scores, hist1);
    scan_hist_kernel<<<B_, 256, 0, stream>>>(hist1, nullptr, B1c, K1c, TOPK_K);
    hist2_kernel<<<NSCORE/256, 256, 0, stream>>>(scores, B1c, hist2);
    scan_hist_kernel<<<B_, 256, 0, stream>>>(hist2, K1c, B2c, K2c, 0u);
    mark_kernel<<<NSCORE/256, 256, 0, stream>>>(scores, B1c, B2c, sel, TIEN, tieIdx);
    ties_kernel<<<1, 64, 0, stream>>>(K2c, TIEN, tieIdx, sel);

    // value path: both up-projections in one launch (z=2), then select+GELU, then down-proj
    bgemm_bt_kernel<<<dim3(H_/128, M_/128, 2), 256, 0, stream>>>(
        (const short*)xb, (const short*)wpb, (const short*)wcb, hprev, hcurr, nullptr, H_, D_);
    act_kernel<<<NSCORE/256, 256, 0, stream>>>(hprev, hcurr, bprev, bcurr, sel, act);
    bgemm_bt_kernel<<<dim3(D_/128, M_/128, 1), 256, 0, stream>>>(
        (const short*)act, (const short*)wdb, (const short*)wdb, out, out, db, D_, H_);
}